// Round 1
// baseline (295.810 us; speedup 1.0000x reference)
//
#include <hip/hip_runtime.h>
#include <math.h>

// Problem constants
#define B_   2
#define F_   4
#define HW_  4096
#define C_   64
#define L_   16384       // F*HW
#define NROWS 32768      // B*F*HW = B*L
#define DI_  96
#define DS_  16
#define DR_  4
#define DC_  4
#define MH_  96
#define CL_  128         // scan chunk length
#define NC_  128         // chunks per batch (L/CL)
#define NPAIR 1536       // DI*DS

// ---------------- K0: tiny prep: mod1/mod2 = cdp @ kernels, Aneg = -exp(A_log)
__global__ void k0_prep(const float* __restrict__ cdp,
                        const float* __restrict__ vd1,
                        const float* __restrict__ vd2,
                        const float* __restrict__ A_log,
                        float* __restrict__ mod1, float* __restrict__ mod2,
                        float* __restrict__ Aneg) {
    int t = threadIdx.x;
    for (int i = t; i < 256; i += 256) {
        int b = i >> 7, j = i & 127;
        float s1 = 0.f, s2 = 0.f;
        for (int k = 0; k < 128; ++k) {
            float c = cdp[b * 128 + k];
            s1 = fmaf(c, vd1[k * 128 + j], s1);
            s2 = fmaf(c, vd2[k * 128 + j], s2);
        }
        mod1[i] = s1; mod2[i] = s2;
    }
    for (int i = t; i < DI_ * DS_; i += 256) Aneg[i] = -__expf(A_log[i]);
}

// ---------------- K1: vdim1 (LN + mod) fused with in_proj GEMM (64 -> 192)
// writes xs_raw (pre-conv, cols 0..95) and zs = silu(z) (cols 96..191)
__global__ __launch_bounds__(256) void k1_vdim1_inproj(
    const float* __restrict__ x, const float* __restrict__ mod1,
    const float* __restrict__ ln_w, const float* __restrict__ ln_b,
    const float* __restrict__ in_proj_w,
    float* __restrict__ xsr, float* __restrict__ zsb) {
    __shared__ float tileX[64][68];
    __shared__ float Wl[64 * 96];
    int t = threadIdx.x;
    int row0 = blockIdx.x * 64;
    int wave = t >> 6, lane = t & 63;
    int b = row0 >> 14;
    const float* m1 = mod1 + b * 128;

    // LayerNorm + modulation: each wave handles 16 rows, lane = channel
    for (int rr = 0; rr < 16; ++rr) {
        int rloc = wave * 16 + rr;
        float v = x[(row0 + rloc) * 64 + lane];
        float s = v, s2 = v * v;
        #pragma unroll
        for (int off = 32; off; off >>= 1) { s += __shfl_xor(s, off); s2 += __shfl_xor(s2, off); }
        float mean = s * (1.0f / 64.0f);
        float var = s2 * (1.0f / 64.0f) - mean * mean;
        float inv = rsqrtf(var + 1e-6f);
        float xn = (v - mean) * inv * ln_w[lane] + ln_b[lane];
        tileX[rloc][lane] = xn * m1[lane] + m1[64 + lane];
    }

    int tc = t & 31, tr = t >> 5;   // tc: 32 col-groups of 3, tr: 8 row-groups of 8
    for (int p = 0; p < 2; ++p) {
        __syncthreads();
        for (int i = t; i < 64 * 96; i += 256) {
            int r = i / 96, c = i % 96;
            Wl[i] = in_proj_w[r * 192 + p * 96 + c];
        }
        __syncthreads();
        float acc[8][3];
        #pragma unroll
        for (int i = 0; i < 8; ++i)
            #pragma unroll
            for (int j = 0; j < 3; ++j) acc[i][j] = 0.f;
        for (int cc = 0; cc < 64; ++cc) {
            float xv[8];
            #pragma unroll
            for (int i = 0; i < 8; ++i) xv[i] = tileX[tr * 8 + i][cc];
            #pragma unroll
            for (int j = 0; j < 3; ++j) {
                float w = Wl[cc * 96 + tc * 3 + j];
                #pragma unroll
                for (int i = 0; i < 8; ++i) acc[i][j] = fmaf(xv[i], w, acc[i][j]);
            }
        }
        float* dst = p == 0 ? xsr : zsb;
        #pragma unroll
        for (int i = 0; i < 8; ++i) {
            int row = row0 + tr * 8 + i;
            #pragma unroll
            for (int j = 0; j < 3; ++j) {
                int col = tc * 3 + j;
                float v = acc[i][j];
                if (p) v = v / (1.0f + __expf(-v));   // silu for z half
                dst[row * 96 + col] = v;
            }
        }
    }
}

// ---------------- K2: causal depthwise conv(k=4) + silu, x_proj (96->36), dt_proj (4->96)+softplus
__global__ __launch_bounds__(256) void k2_conv_dbc_dt(
    const float* __restrict__ xsr,
    const float* __restrict__ conv_w, const float* __restrict__ conv_b,
    const float* __restrict__ x_proj_w,
    const float* __restrict__ dt_proj_w, const float* __restrict__ dt_proj_b,
    float* __restrict__ xsc, float* __restrict__ dtb,
    float* __restrict__ Bm, float* __restrict__ Cm) {
    __shared__ float xin[67][96];
    __shared__ float xst[64][96];
    __shared__ float dbc[64][36];
    int t = threadIdx.x;
    int row0 = blockIdx.x * 64;
    int bbase = row0 & ~16383;   // first row of this batch

    for (int i = t; i < 67 * 96; i += 256) {
        int r = i / 96, d = i % 96;
        int gr = row0 - 3 + r;
        xin[r][d] = (gr >= bbase) ? xsr[gr * 96 + d] : 0.f;
    }
    __syncthreads();

    for (int idx = t; idx < 64 * 96; idx += 256) {
        int l = idx / 96, d = idx % 96;
        float a = conv_b[d];
        #pragma unroll
        for (int k = 0; k < 4; ++k) a = fmaf(xin[l + k][d], conv_w[d * 4 + k], a);
        float sv = a / (1.0f + __expf(-a));
        xst[l][d] = sv;
        xsc[(row0 + l) * 96 + d] = sv;
    }
    __syncthreads();

    for (int idx = t; idx < 64 * 36; idx += 256) {
        int l = idx / 36, j = idx % 36;
        float a = 0.f;
        for (int d = 0; d < 96; ++d) a = fmaf(xst[l][d], x_proj_w[d * 36 + j], a);
        dbc[l][j] = a;
        int row = row0 + l;
        if (j >= 4 && j < 20) Bm[row * 16 + (j - 4)] = a;
        else if (j >= 20)     Cm[row * 16 + (j - 20)] = a;
    }
    __syncthreads();

    for (int idx = t; idx < 64 * 96; idx += 256) {
        int l = idx / 96, d = idx % 96;
        float a = dt_proj_b[d];
        #pragma unroll
        for (int r = 0; r < 4; ++r) a = fmaf(dbc[l][r], dt_proj_w[r * 96 + d], a);
        float sp = fmaxf(a, 0.f) + log1pf(__expf(-fabsf(a)));   // softplus
        dtb[(row0 + l) * 96 + d] = sp;
    }
}

// ---------------- K3: scan pass 1 — per-chunk aggregates (Aprod, Bcomb) per (b,chunk,d,s)
__global__ __launch_bounds__(256) void k3_scan1(
    const float* __restrict__ dtb, const float* __restrict__ xsc,
    const float* __restrict__ Bm, const float* __restrict__ Aneg,
    float2* __restrict__ agg) {
    int t = threadIdx.x;
    int bid = blockIdx.x;            // 0..1535
    int pg = bid % 6;
    int bc = bid / 6;                // b*128 + chunk
    int b = bc >> 7, chunk = bc & 127;
    int pair = pg * 256 + t;
    int d = pair >> 4, s = pair & 15;
    float acoef = Aneg[d * 16 + s];
    int row0 = b * 16384 + chunk * CL_;
    float hA = 1.f, hB = 0.f;
    #pragma unroll 4
    for (int i = 0; i < CL_; ++i) {
        int row = row0 + i;
        float dtv = dtb[row * 96 + d];
        float xv  = xsc[row * 96 + d];
        float bv  = Bm[row * 16 + s];
        float ae  = __expf(dtv * acoef);
        hB = fmaf(hB, ae, dtv * xv * bv);
        hA *= ae;
    }
    agg[bc * NPAIR + pair] = make_float2(hA, hB);
}

// ---------------- K4: scan pass 2 — exclusive scan across chunks per (b,d,s)
__global__ __launch_bounds__(256) void k4_scan2(const float2* __restrict__ agg,
                                                float* __restrict__ initb) {
    int tg = blockIdx.x * 256 + threadIdx.x;   // 0..3071
    int b = tg / NPAIR, pair = tg % NPAIR;
    float h = 0.f;
    for (int chunk = 0; chunk < NC_; ++chunk) {
        int idx = (b * NC_ + chunk) * NPAIR + pair;
        initb[idx] = h;
        float2 ab = agg[idx];
        h = fmaf(h, ab.x, ab.y);
    }
}

// ---------------- K5: scan pass 3 — replay with init state, y = sum_s h*C + D*xs, gate silu(z)
__global__ __launch_bounds__(256) void k5_scan3(
    const float* __restrict__ dtb, const float* __restrict__ xsc,
    const float* __restrict__ Bm, const float* __restrict__ Cm,
    const float* __restrict__ Aneg, const float* __restrict__ initb,
    const float* __restrict__ Dp, const float* __restrict__ zsb,
    float* __restrict__ yb) {
    int t = threadIdx.x;
    int bid = blockIdx.x;
    int pg = bid % 6;
    int bc = bid / 6;
    int b = bc >> 7, chunk = bc & 127;
    int pair = pg * 256 + t;
    int d = pair >> 4, s = pair & 15;
    float acoef = Aneg[d * 16 + s];
    float dcoef = Dp[d];
    int row0 = b * 16384 + chunk * CL_;
    float h = initb[bc * NPAIR + pair];
    for (int i = 0; i < CL_; ++i) {
        int row = row0 + i;
        float dtv = dtb[row * 96 + d];
        float xv  = xsc[row * 96 + d];
        float bv  = Bm[row * 16 + s];
        float cv  = Cm[row * 16 + s];
        float ae  = __expf(dtv * acoef);
        h = fmaf(h, ae, dtv * xv * bv);
        float part = h * cv;
        part += __shfl_xor(part, 8);
        part += __shfl_xor(part, 4);
        part += __shfl_xor(part, 2);
        part += __shfl_xor(part, 1);
        if (s == 0) {
            float yv = part + dcoef * xv;
            yv *= zsb[row * 96 + d];
            yb[row * 96 + d] = yv;
        }
    }
}

// ---------------- K6: out_proj (96->64) + skip1 -> h1
__global__ __launch_bounds__(256) void k6_outproj(
    const float* __restrict__ yb, const float* __restrict__ opw,
    const float* __restrict__ x, const float* __restrict__ ss1,
    float* __restrict__ h1) {
    __shared__ float yt[64][100];
    int t = threadIdx.x;
    int row0 = blockIdx.x * 64;
    for (int i = t; i < 64 * 96; i += 256) {
        int l = i / 96, d = i % 96;
        yt[l][d] = yb[(row0 + l) * 96 + d];
    }
    __syncthreads();
    int tc = t & 15, tr = t >> 4;   // 16 col-groups of 4, 16 row-groups of 4
    float acc[4][4];
    #pragma unroll
    for (int i = 0; i < 4; ++i)
        #pragma unroll
        for (int j = 0; j < 4; ++j) acc[i][j] = 0.f;
    for (int m = 0; m < 96; ++m) {
        float wv[4];
        #pragma unroll
        for (int j = 0; j < 4; ++j) wv[j] = opw[m * 64 + tc * 4 + j];
        #pragma unroll
        for (int i = 0; i < 4; ++i) {
            float yv = yt[tr * 4 + i][m];
            #pragma unroll
            for (int j = 0; j < 4; ++j) acc[i][j] = fmaf(yv, wv[j], acc[i][j]);
        }
    }
    #pragma unroll
    for (int i = 0; i < 4; ++i) {
        int row = row0 + tr * 4 + i;
        #pragma unroll
        for (int j = 0; j < 4; ++j) {
            int c = tc * 4 + j;
            h1[row * 64 + c] = acc[i][j] + x[row * 64 + c] * ss1[c];
        }
    }
}

// ---------------- K7: vdim2 (LN+mod) + MLP (64->96 gelu 96->64) + skip2 -> out
__global__ __launch_bounds__(256) void k7_vdim2_mlp(
    const float* __restrict__ h1, const float* __restrict__ mod2,
    const float* __restrict__ ln2_w, const float* __restrict__ ln2_b,
    const float* __restrict__ fc1_w, const float* __restrict__ fc1_b,
    const float* __restrict__ fc2_w, const float* __restrict__ fc2_b,
    const float* __restrict__ ss2, float* __restrict__ out) {
    __shared__ float x2t[64][68];
    __shared__ float tt[64][100];
    int t = threadIdx.x;
    int row0 = blockIdx.x * 64;
    int wave = t >> 6, lane = t & 63;
    int b = row0 >> 14;
    const float* m2 = mod2 + b * 128;

    for (int rr = 0; rr < 16; ++rr) {
        int rloc = wave * 16 + rr;
        float v = h1[(row0 + rloc) * 64 + lane];
        float s = v, s2 = v * v;
        #pragma unroll
        for (int off = 32; off; off >>= 1) { s += __shfl_xor(s, off); s2 += __shfl_xor(s2, off); }
        float mean = s * (1.0f / 64.0f);
        float var = s2 * (1.0f / 64.0f) - mean * mean;
        float inv = rsqrtf(var + 1e-6f);
        float xn = (v - mean) * inv * ln2_w[lane] + ln2_b[lane];
        x2t[rloc][lane] = xn * m2[lane] + m2[64 + lane];
    }
    __syncthreads();

    // fc1 + exact gelu
    for (int idx = t; idx < 64 * 96; idx += 256) {
        int l = idx / 96, j = idx % 96;
        float a = fc1_b[j];
        for (int c = 0; c < 64; ++c) a = fmaf(x2t[l][c], fc1_w[c * 96 + j], a);
        tt[l][j] = 0.5f * a * (1.f + erff(a * 0.70710678118654752f));
    }
    __syncthreads();

    // fc2 + bias + skip2
    int tc = t & 15, tr = t >> 4;
    float acc[4][4];
    #pragma unroll
    for (int i = 0; i < 4; ++i)
        #pragma unroll
        for (int j = 0; j < 4; ++j) acc[i][j] = 0.f;
    for (int m = 0; m < 96; ++m) {
        float wv[4];
        #pragma unroll
        for (int j = 0; j < 4; ++j) wv[j] = fc2_w[m * 64 + tc * 4 + j];
        #pragma unroll
        for (int i = 0; i < 4; ++i) {
            float tv = tt[tr * 4 + i][m];
            #pragma unroll
            for (int j = 0; j < 4; ++j) acc[i][j] = fmaf(tv, wv[j], acc[i][j]);
        }
    }
    #pragma unroll
    for (int i = 0; i < 4; ++i) {
        int row = row0 + tr * 4 + i;
        #pragma unroll
        for (int j = 0; j < 4; ++j) {
            int c = tc * 4 + j;
            out[row * 64 + c] = h1[row * 64 + c] * ss2[c] + acc[i][j] + fc2_b[c];
        }
    }
}

extern "C" void kernel_launch(void* const* d_in, const int* in_sizes, int n_in,
                              void* d_out, int out_size, void* d_ws, size_t ws_size,
                              hipStream_t stream) {
    const float* x        = (const float*)d_in[0];
    const float* cdp      = (const float*)d_in[1];
    const float* vd1      = (const float*)d_in[2];
    const float* ln1_w    = (const float*)d_in[3];
    const float* ln1_b    = (const float*)d_in[4];
    const float* ss1      = (const float*)d_in[5];
    const float* in_proj  = (const float*)d_in[6];
    const float* conv_w   = (const float*)d_in[7];
    const float* conv_b   = (const float*)d_in[8];
    const float* x_proj   = (const float*)d_in[9];
    const float* dt_w     = (const float*)d_in[10];
    const float* dt_b     = (const float*)d_in[11];
    const float* A_log    = (const float*)d_in[12];
    const float* Dp       = (const float*)d_in[13];
    const float* opw      = (const float*)d_in[14];
    const float* vd2      = (const float*)d_in[15];
    const float* ln2_w    = (const float*)d_in[16];
    const float* ln2_b    = (const float*)d_in[17];
    const float* ss2      = (const float*)d_in[18];
    const float* fc1_w    = (const float*)d_in[19];
    const float* fc1_b    = (const float*)d_in[20];
    const float* fc2_w    = (const float*)d_in[21];
    const float* fc2_b    = (const float*)d_in[22];

    float* ws = (float*)d_ws;
    const size_t NLD = (size_t)B_ * L_ * DI_;     // 3,145,728
    float* mod1  = ws;                            // 256
    float* mod2  = mod1 + 256;                    // 256
    float* Aneg  = mod2 + 256;                    // 1536
    float* xsr   = ws + 2048;                     // NLD  (pre-conv xs)
    float* zsb   = xsr + NLD;                     // NLD  (silu(z))
    float* xsc   = zsb + NLD;                     // NLD  (post-conv xs)
    float* dtb   = xsc + NLD;                     // NLD
    float* Bmb   = dtb + NLD;                     // B*L*DS = 524288
    float* Cmb   = Bmb + (size_t)B_ * L_ * DS_;   // 524288
    float* aggf  = Cmb + (size_t)B_ * L_ * DS_;   // 2*B*NC*NPAIR = 786432 floats
    float* initb = aggf + 2 * (size_t)B_ * NC_ * NPAIR;  // 393216
    float* yb    = initb + (size_t)B_ * NC_ * NPAIR;     // NLD
    float* h1    = yb + NLD;                      // NROWS*C = 2097152
    // total ~20.06M floats = ~80.2 MB

    k0_prep<<<1, 256, 0, stream>>>(cdp, vd1, vd2, A_log, mod1, mod2, Aneg);
    k1_vdim1_inproj<<<NROWS / 64, 256, 0, stream>>>(x, mod1, ln1_w, ln1_b, in_proj, xsr, zsb);
    k2_conv_dbc_dt<<<NROWS / 64, 256, 0, stream>>>(xsr, conv_w, conv_b, x_proj, dt_w, dt_b,
                                                   xsc, dtb, Bmb, Cmb);
    k3_scan1<<<B_ * NC_ * 6, 256, 0, stream>>>(dtb, xsc, Bmb, Aneg, (float2*)aggf);
    k4_scan2<<<(B_ * NPAIR) / 256, 256, 0, stream>>>((const float2*)aggf, initb);
    k5_scan3<<<B_ * NC_ * 6, 256, 0, stream>>>(dtb, xsc, Bmb, Cmb, Aneg, initb, Dp, zsb, yb);
    k6_outproj<<<NROWS / 64, 256, 0, stream>>>(yb, opw, x, ss1, h1);
    k7_vdim2_mlp<<<NROWS / 64, 256, 0, stream>>>(h1, mod2, ln2_w, ln2_b, fc1_w, fc1_b,
                                                 fc2_w, fc2_b, ss2, (float*)d_out);
}

// Round 2
// 241.750 us; speedup vs baseline: 1.2236x; 1.2236x over previous
//
#include <hip/hip_runtime.h>
#include <math.h>

// Problem constants
#define B_   2
#define F_   4
#define HW_  4096
#define C_   64
#define L_   16384       // F*HW
#define NROWS 32768      // B*F*HW = B*L
#define DI_  96
#define DS_  16
#define DR_  4
#define DC_  4
#define MH_  96
#define CL_  64          // scan chunk length
#define NC_  256         // chunks per batch (L/CL)
#define NCT_ 512         // total chunks (B*NC)
#define NPAIR 1536       // DI*DS

// ---------------- K0: tiny prep: mod1/mod2 = cdp @ kernels, Aneg = -exp(A_log)
__global__ void k0_prep(const float* __restrict__ cdp,
                        const float* __restrict__ vd1,
                        const float* __restrict__ vd2,
                        const float* __restrict__ A_log,
                        float* __restrict__ mod1, float* __restrict__ mod2,
                        float* __restrict__ Aneg) {
    int t = threadIdx.x;
    for (int i = t; i < 256; i += 256) {
        int b = i >> 7, j = i & 127;
        float s1 = 0.f, s2 = 0.f;
        for (int k = 0; k < 128; ++k) {
            float c = cdp[b * 128 + k];
            s1 = fmaf(c, vd1[k * 128 + j], s1);
            s2 = fmaf(c, vd2[k * 128 + j], s2);
        }
        mod1[i] = s1; mod2[i] = s2;
    }
    for (int i = t; i < DI_ * DS_; i += 256) Aneg[i] = -__expf(A_log[i]);
}

// ---------------- K1: vdim1 (LN + mod) fused with in_proj GEMM (64 -> 192)
__global__ __launch_bounds__(256) void k1_vdim1_inproj(
    const float* __restrict__ x, const float* __restrict__ mod1,
    const float* __restrict__ ln_w, const float* __restrict__ ln_b,
    const float* __restrict__ in_proj_w,
    float* __restrict__ xsr, float* __restrict__ zsb) {
    __shared__ float tileX[64][68];
    __shared__ float Wl[64 * 96];
    int t = threadIdx.x;
    int row0 = blockIdx.x * 64;
    int wave = t >> 6, lane = t & 63;
    int b = row0 >> 14;
    const float* m1 = mod1 + b * 128;

    for (int rr = 0; rr < 16; ++rr) {
        int rloc = wave * 16 + rr;
        float v = x[(row0 + rloc) * 64 + lane];
        float s = v, s2 = v * v;
        #pragma unroll
        for (int off = 32; off; off >>= 1) { s += __shfl_xor(s, off); s2 += __shfl_xor(s2, off); }
        float mean = s * (1.0f / 64.0f);
        float var = s2 * (1.0f / 64.0f) - mean * mean;
        float inv = rsqrtf(var + 1e-6f);
        float xn = (v - mean) * inv * ln_w[lane] + ln_b[lane];
        tileX[rloc][lane] = xn * m1[lane] + m1[64 + lane];
    }

    int tc = t & 31, tr = t >> 5;
    for (int p = 0; p < 2; ++p) {
        __syncthreads();
        for (int i = t; i < 64 * 96; i += 256) {
            int r = i / 96, c = i % 96;
            Wl[i] = in_proj_w[r * 192 + p * 96 + c];
        }
        __syncthreads();
        float acc[8][3];
        #pragma unroll
        for (int i = 0; i < 8; ++i)
            #pragma unroll
            for (int j = 0; j < 3; ++j) acc[i][j] = 0.f;
        for (int cc = 0; cc < 64; ++cc) {
            float xv[8];
            #pragma unroll
            for (int i = 0; i < 8; ++i) xv[i] = tileX[tr * 8 + i][cc];
            #pragma unroll
            for (int j = 0; j < 3; ++j) {
                float w = Wl[cc * 96 + tc * 3 + j];
                #pragma unroll
                for (int i = 0; i < 8; ++i) acc[i][j] = fmaf(xv[i], w, acc[i][j]);
            }
        }
        float* dst = p == 0 ? xsr : zsb;
        #pragma unroll
        for (int i = 0; i < 8; ++i) {
            int row = row0 + tr * 8 + i;
            #pragma unroll
            for (int j = 0; j < 3; ++j) {
                int col = tc * 3 + j;
                float v = acc[i][j];
                if (p) v = v / (1.0f + __expf(-v));
                dst[row * 96 + col] = v;
            }
        }
    }
}

// ---------------- K2: causal depthwise conv(k=4) + silu, x_proj (96->36), dt_proj (4->96)+softplus
__global__ __launch_bounds__(256) void k2_conv_dbc_dt(
    const float* __restrict__ xsr,
    const float* __restrict__ conv_w, const float* __restrict__ conv_b,
    const float* __restrict__ x_proj_w,
    const float* __restrict__ dt_proj_w, const float* __restrict__ dt_proj_b,
    float* __restrict__ xsc, float* __restrict__ dtb,
    float* __restrict__ Bm, float* __restrict__ Cm) {
    __shared__ float xin[67][96];
    __shared__ float xst[64][96];
    __shared__ float dbc[64][36];
    int t = threadIdx.x;
    int row0 = blockIdx.x * 64;
    int bbase = row0 & ~16383;

    for (int i = t; i < 67 * 96; i += 256) {
        int r = i / 96, d = i % 96;
        int gr = row0 - 3 + r;
        xin[r][d] = (gr >= bbase) ? xsr[gr * 96 + d] : 0.f;
    }
    __syncthreads();

    for (int idx = t; idx < 64 * 96; idx += 256) {
        int l = idx / 96, d = idx % 96;
        float a = conv_b[d];
        #pragma unroll
        for (int k = 0; k < 4; ++k) a = fmaf(xin[l + k][d], conv_w[d * 4 + k], a);
        float sv = a / (1.0f + __expf(-a));
        xst[l][d] = sv;
        xsc[(row0 + l) * 96 + d] = sv;
    }
    __syncthreads();

    for (int idx = t; idx < 64 * 36; idx += 256) {
        int l = idx / 36, j = idx % 36;
        float a = 0.f;
        for (int d = 0; d < 96; ++d) a = fmaf(xst[l][d], x_proj_w[d * 36 + j], a);
        dbc[l][j] = a;
        int row = row0 + l;
        if (j >= 4 && j < 20) Bm[row * 16 + (j - 4)] = a;
        else if (j >= 20)     Cm[row * 16 + (j - 20)] = a;
    }
    __syncthreads();

    for (int idx = t; idx < 64 * 96; idx += 256) {
        int l = idx / 96, d = idx % 96;
        float a = dt_proj_b[d];
        #pragma unroll
        for (int r = 0; r < 4; ++r) a = fmaf(dbc[l][r], dt_proj_w[r * 96 + d], a);
        float sp = fmaxf(a, 0.f) + log1pf(__expf(-fabsf(a)));
        dtb[(row0 + l) * 96 + d] = sp;
    }
}

// ---------------- scan pass 1: per-chunk aggregates. thread = (d, s-quad), 4 states in regs
__global__ __launch_bounds__(384) void s1_agg(
    const float* __restrict__ dtb, const float* __restrict__ xsc,
    const float* __restrict__ Bm, const float* __restrict__ Aneg,
    float2* __restrict__ agg) {
    int t = threadIdx.x;
    int d = t >> 2, sq = t & 3;
    int bc = blockIdx.x;                    // 0..511
    int b = bc >> 8, chunk = bc & 255;
    int row0 = b * L_ + chunk * CL_;
    float4 ac = *(const float4*)&Aneg[d * 16 + sq * 4];
    float a0 = 1.f, a1 = 1.f, a2 = 1.f, a3 = 1.f;
    float b0 = 0.f, b1 = 0.f, b2 = 0.f, b3 = 0.f;
    #pragma unroll 4
    for (int i = 0; i < CL_; ++i) {
        int row = row0 + i;
        float dtv = dtb[row * 96 + d];
        float xv  = xsc[row * 96 + d];
        float4 bv = *(const float4*)&Bm[row * 16 + sq * 4];
        float dx = dtv * xv;
        float e0 = __expf(dtv * ac.x), e1 = __expf(dtv * ac.y);
        float e2 = __expf(dtv * ac.z), e3 = __expf(dtv * ac.w);
        b0 = fmaf(b0, e0, dx * bv.x); a0 *= e0;
        b1 = fmaf(b1, e1, dx * bv.y); a1 *= e1;
        b2 = fmaf(b2, e2, dx * bv.z); a2 *= e2;
        b3 = fmaf(b3, e3, dx * bv.w); a3 *= e3;
    }
    size_t base = (size_t)bc * NPAIR + d * 16 + sq * 4;
    *(float4*)&agg[base]     = make_float4(a0, b0, a1, b1);
    *(float4*)&agg[base + 2] = make_float4(a2, b2, a3, b3);
}

// ---------------- scan pass 2: Hillis-Steele scan across 256 chunks, block per (b,pair)
__global__ __launch_bounds__(256) void s2_scan(const float2* __restrict__ agg,
                                               float* __restrict__ initb) {
    __shared__ float sA[256], sB[256];
    int seq = blockIdx.x;                   // 0..3071
    int b = seq / NPAIR, pair = seq % NPAIR;
    int c = threadIdx.x;                    // chunk
    float2 v = agg[((size_t)(b * NC_ + c)) * NPAIR + pair];
    sA[c] = v.x; sB[c] = v.y;
    #pragma unroll
    for (int off = 1; off < 256; off <<= 1) {
        __syncthreads();
        float ap = 0.f, bp = 0.f;
        bool has = c >= off;
        if (has) { ap = sA[c - off]; bp = sB[c - off]; }
        __syncthreads();
        if (has) { sB[c] = fmaf(bp, sA[c], sB[c]); sA[c] *= ap; }
    }
    __syncthreads();
    float init = (c == 0) ? 0.f : sB[c - 1];
    initb[((size_t)(b * NC_ + c)) * NPAIR + pair] = init;
}

// ---------------- scan pass 3: replay + y = sum_s h*C + D*xs, gate silu(z)
__global__ __launch_bounds__(384) void s3_replay(
    const float* __restrict__ dtb, const float* __restrict__ xsc,
    const float* __restrict__ Bm, const float* __restrict__ Cm,
    const float* __restrict__ Aneg, const float* __restrict__ initb,
    const float* __restrict__ Dp, const float* __restrict__ zsb,
    float* __restrict__ yb) {
    int t = threadIdx.x;
    int d = t >> 2, sq = t & 3;
    int bc = blockIdx.x;
    int b = bc >> 8, chunk = bc & 255;
    int row0 = b * L_ + chunk * CL_;
    float4 ac = *(const float4*)&Aneg[d * 16 + sq * 4];
    float dcoef = Dp[d];
    float4 hv = *(const float4*)&initb[(size_t)bc * NPAIR + d * 16 + sq * 4];
    float h0 = hv.x, h1 = hv.y, h2 = hv.z, h3 = hv.w;
    #pragma unroll 2
    for (int i = 0; i < CL_; ++i) {
        int row = row0 + i;
        float dtv = dtb[row * 96 + d];
        float xv  = xsc[row * 96 + d];
        float4 bv = *(const float4*)&Bm[row * 16 + sq * 4];
        float4 cv = *(const float4*)&Cm[row * 16 + sq * 4];
        float dx = dtv * xv;
        float e0 = __expf(dtv * ac.x), e1 = __expf(dtv * ac.y);
        float e2 = __expf(dtv * ac.z), e3 = __expf(dtv * ac.w);
        h0 = fmaf(h0, e0, dx * bv.x);
        h1 = fmaf(h1, e1, dx * bv.y);
        h2 = fmaf(h2, e2, dx * bv.z);
        h3 = fmaf(h3, e3, dx * bv.w);
        float part = h0 * cv.x;
        part = fmaf(h1, cv.y, part);
        part = fmaf(h2, cv.z, part);
        part = fmaf(h3, cv.w, part);
        part += __shfl_xor(part, 1);
        part += __shfl_xor(part, 2);
        if (sq == 0) {
            float yv = part + dcoef * xv;
            yb[row * 96 + d] = yv * zsb[row * 96 + d];
        }
    }
}

// ---------------- K6: out_proj (96->64) + skip1 -> h1
__global__ __launch_bounds__(256) void k6_outproj(
    const float* __restrict__ yb, const float* __restrict__ opw,
    const float* __restrict__ x, const float* __restrict__ ss1,
    float* __restrict__ h1) {
    __shared__ float yt[64][100];
    int t = threadIdx.x;
    int row0 = blockIdx.x * 64;
    for (int i = t; i < 64 * 96; i += 256) {
        int l = i / 96, d = i % 96;
        yt[l][d] = yb[(row0 + l) * 96 + d];
    }
    __syncthreads();
    int tc = t & 15, tr = t >> 4;
    float acc[4][4];
    #pragma unroll
    for (int i = 0; i < 4; ++i)
        #pragma unroll
        for (int j = 0; j < 4; ++j) acc[i][j] = 0.f;
    for (int m = 0; m < 96; ++m) {
        float wv[4];
        #pragma unroll
        for (int j = 0; j < 4; ++j) wv[j] = opw[m * 64 + tc * 4 + j];
        #pragma unroll
        for (int i = 0; i < 4; ++i) {
            float yv = yt[tr * 4 + i][m];
            #pragma unroll
            for (int j = 0; j < 4; ++j) acc[i][j] = fmaf(yv, wv[j], acc[i][j]);
        }
    }
    #pragma unroll
    for (int i = 0; i < 4; ++i) {
        int row = row0 + tr * 4 + i;
        #pragma unroll
        for (int j = 0; j < 4; ++j) {
            int c = tc * 4 + j;
            h1[row * 64 + c] = acc[i][j] + x[row * 64 + c] * ss1[c];
        }
    }
}

// ---------------- K7: vdim2 (LN+mod) + MLP (64->96 gelu 96->64) + skip2 -> out
__global__ __launch_bounds__(256) void k7_vdim2_mlp(
    const float* __restrict__ h1, const float* __restrict__ mod2,
    const float* __restrict__ ln2_w, const float* __restrict__ ln2_b,
    const float* __restrict__ fc1_w, const float* __restrict__ fc1_b,
    const float* __restrict__ fc2_w, const float* __restrict__ fc2_b,
    const float* __restrict__ ss2, float* __restrict__ out) {
    __shared__ float x2t[64][68];
    __shared__ float tt[64][100];
    int t = threadIdx.x;
    int row0 = blockIdx.x * 64;
    int wave = t >> 6, lane = t & 63;
    int b = row0 >> 14;
    const float* m2 = mod2 + b * 128;

    for (int rr = 0; rr < 16; ++rr) {
        int rloc = wave * 16 + rr;
        float v = h1[(row0 + rloc) * 64 + lane];
        float s = v, s2 = v * v;
        #pragma unroll
        for (int off = 32; off; off >>= 1) { s += __shfl_xor(s, off); s2 += __shfl_xor(s2, off); }
        float mean = s * (1.0f / 64.0f);
        float var = s2 * (1.0f / 64.0f) - mean * mean;
        float inv = rsqrtf(var + 1e-6f);
        float xn = (v - mean) * inv * ln2_w[lane] + ln2_b[lane];
        x2t[rloc][lane] = xn * m2[lane] + m2[64 + lane];
    }
    __syncthreads();

    for (int idx = t; idx < 64 * 96; idx += 256) {
        int l = idx / 96, j = idx % 96;
        float a = fc1_b[j];
        for (int c = 0; c < 64; ++c) a = fmaf(x2t[l][c], fc1_w[c * 96 + j], a);
        tt[l][j] = 0.5f * a * (1.f + erff(a * 0.70710678118654752f));
    }
    __syncthreads();

    int tc = t & 15, tr = t >> 4;
    float acc[4][4];
    #pragma unroll
    for (int i = 0; i < 4; ++i)
        #pragma unroll
        for (int j = 0; j < 4; ++j) acc[i][j] = 0.f;
    for (int m = 0; m < 96; ++m) {
        float wv[4];
        #pragma unroll
        for (int j = 0; j < 4; ++j) wv[j] = fc2_w[m * 64 + tc * 4 + j];
        #pragma unroll
        for (int i = 0; i < 4; ++i) {
            float tv = tt[tr * 4 + i][m];
            #pragma unroll
            for (int j = 0; j < 4; ++j) acc[i][j] = fmaf(tv, wv[j], acc[i][j]);
        }
    }
    #pragma unroll
    for (int i = 0; i < 4; ++i) {
        int row = row0 + tr * 4 + i;
        #pragma unroll
        for (int j = 0; j < 4; ++j) {
            int c = tc * 4 + j;
            out[row * 64 + c] = h1[row * 64 + c] * ss2[c] + acc[i][j] + fc2_b[c];
        }
    }
}

extern "C" void kernel_launch(void* const* d_in, const int* in_sizes, int n_in,
                              void* d_out, int out_size, void* d_ws, size_t ws_size,
                              hipStream_t stream) {
    const float* x        = (const float*)d_in[0];
    const float* cdp      = (const float*)d_in[1];
    const float* vd1      = (const float*)d_in[2];
    const float* ln1_w    = (const float*)d_in[3];
    const float* ln1_b    = (const float*)d_in[4];
    const float* ss1      = (const float*)d_in[5];
    const float* in_proj  = (const float*)d_in[6];
    const float* conv_w   = (const float*)d_in[7];
    const float* conv_b   = (const float*)d_in[8];
    const float* x_proj   = (const float*)d_in[9];
    const float* dt_w     = (const float*)d_in[10];
    const float* dt_b     = (const float*)d_in[11];
    const float* A_log    = (const float*)d_in[12];
    const float* Dp       = (const float*)d_in[13];
    const float* opw      = (const float*)d_in[14];
    const float* vd2      = (const float*)d_in[15];
    const float* ln2_w    = (const float*)d_in[16];
    const float* ln2_b    = (const float*)d_in[17];
    const float* ss2      = (const float*)d_in[18];
    const float* fc1_w    = (const float*)d_in[19];
    const float* fc1_b    = (const float*)d_in[20];
    const float* fc2_w    = (const float*)d_in[21];
    const float* fc2_b    = (const float*)d_in[22];

    float* ws = (float*)d_ws;
    const size_t NLD = (size_t)B_ * L_ * DI_;     // 3,145,728
    float* mod1  = ws;                            // 256
    float* mod2  = mod1 + 256;                    // 256
    float* Aneg  = mod2 + 256;                    // 1536
    float* xsr   = ws + 2048;                     // NLD  (pre-conv xs; later reused as yb)
    float* zsb   = xsr + NLD;                     // NLD  (silu(z); later reused as h1)
    float* xsc   = zsb + NLD;                     // NLD
    float* dtb   = xsc + NLD;                     // NLD
    float* Bmb   = dtb + NLD;                     // 524288
    float* Cmb   = Bmb + (size_t)B_ * L_ * DS_;   // 524288
    float* aggf  = Cmb + (size_t)B_ * L_ * DS_;   // 2*NCT*NPAIR = 1,572,864 floats
    float* initb = aggf + 2 * (size_t)NCT_ * NPAIR; // NCT*NPAIR = 786,432
    // total = 2048 + 4*NLD + 2*524288 + 1572864 + 786432 ≈ 16.0M floats = 64 MB
    float* yb = xsr;   // xsr dead after k2
    float* h1 = zsb;   // zsb dead after s3_replay

    k0_prep<<<1, 256, 0, stream>>>(cdp, vd1, vd2, A_log, mod1, mod2, Aneg);
    k1_vdim1_inproj<<<NROWS / 64, 256, 0, stream>>>(x, mod1, ln1_w, ln1_b, in_proj, xsr, zsb);
    k2_conv_dbc_dt<<<NROWS / 64, 256, 0, stream>>>(xsr, conv_w, conv_b, x_proj, dt_w, dt_b,
                                                   xsc, dtb, Bmb, Cmb);
    s1_agg<<<NCT_, 384, 0, stream>>>(dtb, xsc, Bmb, Aneg, (float2*)aggf);
    s2_scan<<<B_ * NPAIR, 256, 0, stream>>>((const float2*)aggf, initb);
    s3_replay<<<NCT_, 384, 0, stream>>>(dtb, xsc, Bmb, Cmb, Aneg, initb, Dp, zsb, yb);
    k6_outproj<<<NROWS / 64, 256, 0, stream>>>(yb, opw, x, ss1, h1);
    k7_vdim2_mlp<<<NROWS / 64, 256, 0, stream>>>(h1, mod2, ln2_w, ln2_b, fc1_w, fc1_b,
                                                 fc2_w, fc2_b, ss2, (float*)d_out);
}

// Round 3
// 222.710 us; speedup vs baseline: 1.3282x; 1.0855x over previous
//
#include <hip/hip_runtime.h>
#include <math.h>

// Problem constants
#define B_   2
#define F_   4
#define HW_  4096
#define C_   64
#define L_   16384       // F*HW
#define NROWS 32768      // B*F*HW = B*L
#define DI_  96
#define DS_  16
#define DR_  4
#define DC_  4
#define MH_  96
#define CL_  64          // scan chunk length
#define NC_  256         // chunks per batch (L/CL)
#define NCT_ 512         // total chunks (B*NC)
#define NPAIR 1536       // DI*DS

// ---------------- K0: tiny prep: mod1/mod2 = cdp @ kernels, Aneg = -exp(A_log)
__global__ void k0_prep(const float* __restrict__ cdp,
                        const float* __restrict__ vd1,
                        const float* __restrict__ vd2,
                        const float* __restrict__ A_log,
                        float* __restrict__ mod1, float* __restrict__ mod2,
                        float* __restrict__ Aneg) {
    int t = threadIdx.x;
    for (int i = t; i < 256; i += 256) {
        int b = i >> 7, j = i & 127;
        float s1 = 0.f, s2 = 0.f;
        for (int k = 0; k < 128; ++k) {
            float c = cdp[b * 128 + k];
            s1 = fmaf(c, vd1[k * 128 + j], s1);
            s2 = fmaf(c, vd2[k * 128 + j], s2);
        }
        mod1[i] = s1; mod2[i] = s2;
    }
    for (int i = t; i < DI_ * DS_; i += 256) Aneg[i] = -__expf(A_log[i]);
}

// ---------------- K1: vdim1 (LN + mod) fused with in_proj GEMM (64 -> 192)
// 32 rows/block; 2 rows x 12 cols per thread; weights straight from L1/L2.
__global__ __launch_bounds__(256) void k1_vdim1_inproj(
    const float* __restrict__ x, const float* __restrict__ mod1,
    const float* __restrict__ ln_w, const float* __restrict__ ln_b,
    const float* __restrict__ in_proj_w,
    float* __restrict__ xsr, float* __restrict__ zsb) {
    __shared__ float tileX[32][66];
    int t = threadIdx.x;
    int row0 = blockIdx.x * 32;
    int wave = t >> 6, lane = t & 63;
    int b = row0 >> 14;
    const float* m1 = mod1 + b * 128;

    // LayerNorm + modulation: 4 waves x 8 rows, lane = channel
    for (int rr = 0; rr < 8; ++rr) {
        int rloc = wave * 8 + rr;
        float v = x[(row0 + rloc) * 64 + lane];
        float s = v, s2 = v * v;
        #pragma unroll
        for (int off = 32; off; off >>= 1) { s += __shfl_xor(s, off); s2 += __shfl_xor(s2, off); }
        float mean = s * (1.0f / 64.0f);
        float var = s2 * (1.0f / 64.0f) - mean * mean;
        float inv = rsqrtf(var + 1e-6f);
        float xn = (v - mean) * inv * ln_w[lane] + ln_b[lane];
        tileX[rloc][lane] = xn * m1[lane] + m1[64 + lane];
    }
    __syncthreads();

    int tr = t >> 4;          // 16 row-groups of 2
    int tc = t & 15;          // 16 col-groups of 12 (cols tc*12 .. +11 in 0..191)
    float acc[2][12];
    #pragma unroll
    for (int i = 0; i < 2; ++i)
        #pragma unroll
        for (int j = 0; j < 12; ++j) acc[i][j] = 0.f;
    for (int c = 0; c < 64; ++c) {
        float x0 = tileX[tr * 2][c];
        float x1 = tileX[tr * 2 + 1][c];
        const float* wp = &in_proj_w[c * 192 + tc * 12];
        float4 wa = *(const float4*)wp;
        float4 wb = *(const float4*)(wp + 4);
        float4 wc = *(const float4*)(wp + 8);
        float w[12] = {wa.x, wa.y, wa.z, wa.w, wb.x, wb.y, wb.z, wb.w, wc.x, wc.y, wc.z, wc.w};
        #pragma unroll
        for (int j = 0; j < 12; ++j) {
            acc[0][j] = fmaf(x0, w[j], acc[0][j]);
            acc[1][j] = fmaf(x1, w[j], acc[1][j]);
        }
    }
    #pragma unroll
    for (int i = 0; i < 2; ++i) {
        int row = row0 + tr * 2 + i;
        if (tc < 8) {
            // xs half: cols tc*12 .. +11 in 0..95
            #pragma unroll
            for (int j = 0; j < 12; ++j)
                xsr[row * 96 + tc * 12 + j] = acc[i][j];
        } else {
            // z half: silu
            #pragma unroll
            for (int j = 0; j < 12; ++j) {
                float v = acc[i][j];
                zsb[row * 96 + (tc - 8) * 12 + j] = v / (1.0f + __expf(-v));
            }
        }
    }
}

// ---------------- K2: causal depthwise conv(k=4) + silu, x_proj (96->36), dt_proj (4->96)+softplus
__global__ __launch_bounds__(256) void k2_conv_dbc_dt(
    const float* __restrict__ xsr,
    const float* __restrict__ conv_w, const float* __restrict__ conv_b,
    const float* __restrict__ x_proj_w,
    const float* __restrict__ dt_proj_w, const float* __restrict__ dt_proj_b,
    float* __restrict__ xsc, float* __restrict__ dtb,
    float* __restrict__ Bm, float* __restrict__ Cm) {
    __shared__ float xin[67][96];
    __shared__ float xst[64][96];
    __shared__ float dbc4[64][4];
    int t = threadIdx.x;
    int row0 = blockIdx.x * 64;
    int bbase = row0 & ~16383;

    for (int i = t; i < 67 * 96; i += 256) {
        int r = i / 96, d = i % 96;
        int gr = row0 - 3 + r;
        xin[r][d] = (gr >= bbase) ? xsr[gr * 96 + d] : 0.f;
    }
    __syncthreads();

    for (int idx = t; idx < 64 * 96; idx += 256) {
        int l = idx / 96, d = idx % 96;
        float a = conv_b[d];
        #pragma unroll
        for (int k = 0; k < 4; ++k) a = fmaf(xin[l + k][d], conv_w[d * 4 + k], a);
        float sv = a / (1.0f + __expf(-a));
        xst[l][d] = sv;
        xsc[(row0 + l) * 96 + d] = sv;
    }
    __syncthreads();

    for (int idx = t; idx < 64 * 36; idx += 256) {
        int l = idx / 36, j = idx % 36;
        float a0 = 0.f, a1 = 0.f, a2 = 0.f, a3 = 0.f;
        #pragma unroll
        for (int d = 0; d < 96; d += 4) {
            a0 = fmaf(xst[l][d],     x_proj_w[d * 36 + j],        a0);
            a1 = fmaf(xst[l][d + 1], x_proj_w[(d + 1) * 36 + j],  a1);
            a2 = fmaf(xst[l][d + 2], x_proj_w[(d + 2) * 36 + j],  a2);
            a3 = fmaf(xst[l][d + 3], x_proj_w[(d + 3) * 36 + j],  a3);
        }
        float a = (a0 + a1) + (a2 + a3);
        int row = row0 + l;
        if (j < 4) dbc4[l][j] = a;
        else if (j < 20) Bm[row * 16 + (j - 4)] = a;
        else             Cm[row * 16 + (j - 20)] = a;
    }
    __syncthreads();

    for (int idx = t; idx < 64 * 96; idx += 256) {
        int l = idx / 96, d = idx % 96;
        float a = dt_proj_b[d];
        #pragma unroll
        for (int r = 0; r < 4; ++r) a = fmaf(dbc4[l][r], dt_proj_w[r * 96 + d], a);
        float sp = fmaxf(a, 0.f) + log1pf(__expf(-fabsf(a)));
        dtb[(row0 + l) * 96 + d] = sp;
    }
}

// ---------------- scan pass 1: per-chunk aggregates. thread = (d, s-quad), 4 states in regs
__global__ __launch_bounds__(384) void s1_agg(
    const float* __restrict__ dtb, const float* __restrict__ xsc,
    const float* __restrict__ Bm, const float* __restrict__ Aneg,
    float2* __restrict__ agg) {
    int t = threadIdx.x;
    int d = t >> 2, sq = t & 3;
    int bc = blockIdx.x;                    // 0..511
    int b = bc >> 8, chunk = bc & 255;
    int row0 = b * L_ + chunk * CL_;
    float4 ac = *(const float4*)&Aneg[d * 16 + sq * 4];
    float a0 = 1.f, a1 = 1.f, a2 = 1.f, a3 = 1.f;
    float b0 = 0.f, b1 = 0.f, b2 = 0.f, b3 = 0.f;
    #pragma unroll 4
    for (int i = 0; i < CL_; ++i) {
        int row = row0 + i;
        float dtv = dtb[row * 96 + d];
        float xv  = xsc[row * 96 + d];
        float4 bv = *(const float4*)&Bm[row * 16 + sq * 4];
        float dx = dtv * xv;
        float e0 = __expf(dtv * ac.x), e1 = __expf(dtv * ac.y);
        float e2 = __expf(dtv * ac.z), e3 = __expf(dtv * ac.w);
        b0 = fmaf(b0, e0, dx * bv.x); a0 *= e0;
        b1 = fmaf(b1, e1, dx * bv.y); a1 *= e1;
        b2 = fmaf(b2, e2, dx * bv.z); a2 *= e2;
        b3 = fmaf(b3, e3, dx * bv.w); a3 *= e3;
    }
    size_t base = (size_t)bc * NPAIR + d * 16 + sq * 4;
    *(float4*)&agg[base]     = make_float4(a0, b0, a1, b1);
    *(float4*)&agg[base + 2] = make_float4(a2, b2, a3, b3);
}

// ---------------- scan pass 2: Hillis-Steele scan across 256 chunks, block per (b,pair)
__global__ __launch_bounds__(256) void s2_scan(const float2* __restrict__ agg,
                                               float* __restrict__ initb) {
    __shared__ float sA[256], sB[256];
    int seq = blockIdx.x;                   // 0..3071
    int b = seq / NPAIR, pair = seq % NPAIR;
    int c = threadIdx.x;                    // chunk
    float2 v = agg[((size_t)(b * NC_ + c)) * NPAIR + pair];
    sA[c] = v.x; sB[c] = v.y;
    #pragma unroll
    for (int off = 1; off < 256; off <<= 1) {
        __syncthreads();
        float ap = 0.f, bp = 0.f;
        bool has = c >= off;
        if (has) { ap = sA[c - off]; bp = sB[c - off]; }
        __syncthreads();
        if (has) { sB[c] = fmaf(bp, sA[c], sB[c]); sA[c] *= ap; }
    }
    __syncthreads();
    float init = (c == 0) ? 0.f : sB[c - 1];
    initb[((size_t)(b * NC_ + c)) * NPAIR + pair] = init;
}

// ---------------- scan pass 3: replay + y = sum_s h*C + D*xs, gate silu(z)
__global__ __launch_bounds__(384) void s3_replay(
    const float* __restrict__ dtb, const float* __restrict__ xsc,
    const float* __restrict__ Bm, const float* __restrict__ Cm,
    const float* __restrict__ Aneg, const float* __restrict__ initb,
    const float* __restrict__ Dp, const float* __restrict__ zsb,
    float* __restrict__ yb) {
    int t = threadIdx.x;
    int d = t >> 2, sq = t & 3;
    int bc = blockIdx.x;
    int b = bc >> 8, chunk = bc & 255;
    int row0 = b * L_ + chunk * CL_;
    float4 ac = *(const float4*)&Aneg[d * 16 + sq * 4];
    float dcoef = Dp[d];
    float4 hv = *(const float4*)&initb[(size_t)bc * NPAIR + d * 16 + sq * 4];
    float h0 = hv.x, h1 = hv.y, h2 = hv.z, h3 = hv.w;
    #pragma unroll 2
    for (int i = 0; i < CL_; ++i) {
        int row = row0 + i;
        float dtv = dtb[row * 96 + d];
        float xv  = xsc[row * 96 + d];
        float4 bv = *(const float4*)&Bm[row * 16 + sq * 4];
        float4 cv = *(const float4*)&Cm[row * 16 + sq * 4];
        float dx = dtv * xv;
        float e0 = __expf(dtv * ac.x), e1 = __expf(dtv * ac.y);
        float e2 = __expf(dtv * ac.z), e3 = __expf(dtv * ac.w);
        h0 = fmaf(h0, e0, dx * bv.x);
        h1 = fmaf(h1, e1, dx * bv.y);
        h2 = fmaf(h2, e2, dx * bv.z);
        h3 = fmaf(h3, e3, dx * bv.w);
        float part = h0 * cv.x;
        part = fmaf(h1, cv.y, part);
        part = fmaf(h2, cv.z, part);
        part = fmaf(h3, cv.w, part);
        part += __shfl_xor(part, 1);
        part += __shfl_xor(part, 2);
        if (sq == 0) {
            float yv = part + dcoef * xv;
            yb[row * 96 + d] = yv * zsb[row * 96 + d];
        }
    }
}

// ---------------- K6: out_proj (96->64) + skip1 -> h1. 32 rows/block, 2x4 per thread.
__global__ __launch_bounds__(256) void k6_outproj(
    const float* __restrict__ yb, const float* __restrict__ opw,
    const float* __restrict__ x, const float* __restrict__ ss1,
    float* __restrict__ h1) {
    __shared__ float yt[32][100];
    int t = threadIdx.x;
    int row0 = blockIdx.x * 32;
    for (int i = t; i < 32 * 96; i += 256) {
        int l = i / 96, d = i % 96;
        yt[l][d] = yb[(row0 + l) * 96 + d];
    }
    __syncthreads();
    int tr = t >> 4, tc = t & 15;   // 2 rows, 4 cols per thread
    float acc[2][4];
    #pragma unroll
    for (int i = 0; i < 2; ++i)
        #pragma unroll
        for (int j = 0; j < 4; ++j) acc[i][j] = 0.f;
    for (int m = 0; m < 96; ++m) {
        float4 wv = *(const float4*)&opw[m * 64 + tc * 4];
        float y0 = yt[tr * 2][m];
        float y1 = yt[tr * 2 + 1][m];
        acc[0][0] = fmaf(y0, wv.x, acc[0][0]); acc[0][1] = fmaf(y0, wv.y, acc[0][1]);
        acc[0][2] = fmaf(y0, wv.z, acc[0][2]); acc[0][3] = fmaf(y0, wv.w, acc[0][3]);
        acc[1][0] = fmaf(y1, wv.x, acc[1][0]); acc[1][1] = fmaf(y1, wv.y, acc[1][1]);
        acc[1][2] = fmaf(y1, wv.z, acc[1][2]); acc[1][3] = fmaf(y1, wv.w, acc[1][3]);
    }
    float4 sv = *(const float4*)&ss1[tc * 4];
    #pragma unroll
    for (int i = 0; i < 2; ++i) {
        int row = row0 + tr * 2 + i;
        float4 xv = *(const float4*)&x[row * 64 + tc * 4];
        float4 o;
        o.x = acc[i][0] + xv.x * sv.x;
        o.y = acc[i][1] + xv.y * sv.y;
        o.z = acc[i][2] + xv.z * sv.z;
        o.w = acc[i][3] + xv.w * sv.w;
        *(float4*)&h1[row * 64 + tc * 4] = o;
    }
}

// ---------------- K7: vdim2 (LN+mod) + MLP (64->96 gelu 96->64) + skip2 -> out
// 32 rows/block: LDS 21KB -> 7 blocks/CU. fc1: 2x6 per thread; fc2: 2x4 per thread.
__global__ __launch_bounds__(256) void k7_vdim2_mlp(
    const float* __restrict__ h1, const float* __restrict__ mod2,
    const float* __restrict__ ln2_w, const float* __restrict__ ln2_b,
    const float* __restrict__ fc1_w, const float* __restrict__ fc1_b,
    const float* __restrict__ fc2_w, const float* __restrict__ fc2_b,
    const float* __restrict__ ss2, float* __restrict__ out) {
    __shared__ float x2t[32][66];
    __shared__ float tt[32][100];
    int t = threadIdx.x;
    int row0 = blockIdx.x * 32;
    int wave = t >> 6, lane = t & 63;
    int b = row0 >> 14;
    const float* m2 = mod2 + b * 128;

    for (int rr = 0; rr < 8; ++rr) {
        int rloc = wave * 8 + rr;
        float v = h1[(row0 + rloc) * 64 + lane];
        float s = v, s2 = v * v;
        #pragma unroll
        for (int off = 32; off; off >>= 1) { s += __shfl_xor(s, off); s2 += __shfl_xor(s2, off); }
        float mean = s * (1.0f / 64.0f);
        float var = s2 * (1.0f / 64.0f) - mean * mean;
        float inv = rsqrtf(var + 1e-6f);
        float xn = (v - mean) * inv * ln2_w[lane] + ln2_b[lane];
        x2t[rloc][lane] = xn * m2[lane] + m2[64 + lane];
    }
    __syncthreads();

    // fc1 + exact gelu: 2 rows x 6 cols per thread
    {
        int tr = t >> 4, tc = t & 15;   // rows 2*tr..+1, cols 6*tc..+5
        float acc[2][6];
        #pragma unroll
        for (int i = 0; i < 2; ++i)
            #pragma unroll
            for (int j = 0; j < 6; ++j) acc[i][j] = 0.f;
        for (int c = 0; c < 64; ++c) {
            float x0 = x2t[tr * 2][c];
            float x1 = x2t[tr * 2 + 1][c];
            const float* wp = &fc1_w[c * 96 + tc * 6];
            float2 w01 = *(const float2*)wp;
            float2 w23 = *(const float2*)(wp + 2);
            float2 w45 = *(const float2*)(wp + 4);
            float w[6] = {w01.x, w01.y, w23.x, w23.y, w45.x, w45.y};
            #pragma unroll
            for (int j = 0; j < 6; ++j) {
                acc[0][j] = fmaf(x0, w[j], acc[0][j]);
                acc[1][j] = fmaf(x1, w[j], acc[1][j]);
            }
        }
        #pragma unroll
        for (int i = 0; i < 2; ++i) {
            #pragma unroll
            for (int j = 0; j < 6; ++j) {
                float a = acc[i][j] + fc1_b[tc * 6 + j];
                tt[tr * 2 + i][tc * 6 + j] = 0.5f * a * (1.f + erff(a * 0.70710678118654752f));
            }
        }
    }
    __syncthreads();

    // fc2 + bias + skip2: 2 rows x 4 cols per thread
    {
        int tr = t >> 4, tc = t & 15;
        float acc[2][4];
        #pragma unroll
        for (int i = 0; i < 2; ++i)
            #pragma unroll
            for (int j = 0; j < 4; ++j) acc[i][j] = 0.f;
        for (int m = 0; m < 96; ++m) {
            float4 wv = *(const float4*)&fc2_w[m * 64 + tc * 4];
            float t0 = tt[tr * 2][m];
            float t1 = tt[tr * 2 + 1][m];
            acc[0][0] = fmaf(t0, wv.x, acc[0][0]); acc[0][1] = fmaf(t0, wv.y, acc[0][1]);
            acc[0][2] = fmaf(t0, wv.z, acc[0][2]); acc[0][3] = fmaf(t0, wv.w, acc[0][3]);
            acc[1][0] = fmaf(t1, wv.x, acc[1][0]); acc[1][1] = fmaf(t1, wv.y, acc[1][1]);
            acc[1][2] = fmaf(t1, wv.z, acc[1][2]); acc[1][3] = fmaf(t1, wv.w, acc[1][3]);
        }
        float4 sv = *(const float4*)&ss2[tc * 4];
        float4 bv = *(const float4*)&fc2_b[tc * 4];
        #pragma unroll
        for (int i = 0; i < 2; ++i) {
            int row = row0 + tr * 2 + i;
            float4 hv = *(const float4*)&h1[row * 64 + tc * 4];
            float4 o;
            o.x = hv.x * sv.x + acc[i][0] + bv.x;
            o.y = hv.y * sv.y + acc[i][1] + bv.y;
            o.z = hv.z * sv.z + acc[i][2] + bv.z;
            o.w = hv.w * sv.w + acc[i][3] + bv.w;
            *(float4*)&out[row * 64 + tc * 4] = o;
        }
    }
}

extern "C" void kernel_launch(void* const* d_in, const int* in_sizes, int n_in,
                              void* d_out, int out_size, void* d_ws, size_t ws_size,
                              hipStream_t stream) {
    const float* x        = (const float*)d_in[0];
    const float* cdp      = (const float*)d_in[1];
    const float* vd1      = (const float*)d_in[2];
    const float* ln1_w    = (const float*)d_in[3];
    const float* ln1_b    = (const float*)d_in[4];
    const float* ss1      = (const float*)d_in[5];
    const float* in_proj  = (const float*)d_in[6];
    const float* conv_w   = (const float*)d_in[7];
    const float* conv_b   = (const float*)d_in[8];
    const float* x_proj   = (const float*)d_in[9];
    const float* dt_w     = (const float*)d_in[10];
    const float* dt_b     = (const float*)d_in[11];
    const float* A_log    = (const float*)d_in[12];
    const float* Dp       = (const float*)d_in[13];
    const float* opw      = (const float*)d_in[14];
    const float* vd2      = (const float*)d_in[15];
    const float* ln2_w    = (const float*)d_in[16];
    const float* ln2_b    = (const float*)d_in[17];
    const float* ss2      = (const float*)d_in[18];
    const float* fc1_w    = (const float*)d_in[19];
    const float* fc1_b    = (const float*)d_in[20];
    const float* fc2_w    = (const float*)d_in[21];
    const float* fc2_b    = (const float*)d_in[22];

    float* ws = (float*)d_ws;
    const size_t NLD = (size_t)B_ * L_ * DI_;     // 3,145,728
    float* mod1  = ws;                            // 256
    float* mod2  = mod1 + 256;                    // 256
    float* Aneg  = mod2 + 256;                    // 1536
    float* xsr   = ws + 2048;                     // NLD  (pre-conv xs; later reused as yb)
    float* zsb   = xsr + NLD;                     // NLD  (silu(z); later reused as h1)
    float* xsc   = zsb + NLD;                     // NLD
    float* dtb   = xsc + NLD;                     // NLD
    float* Bmb   = dtb + NLD;                     // 524288
    float* Cmb   = Bmb + (size_t)B_ * L_ * DS_;   // 524288
    float* aggf  = Cmb + (size_t)B_ * L_ * DS_;   // 2*NCT*NPAIR
    float* initb = aggf + 2 * (size_t)NCT_ * NPAIR; // NCT*NPAIR
    float* yb = xsr;   // xsr dead after k2
    float* h1 = zsb;   // zsb dead after s3_replay

    k0_prep<<<1, 256, 0, stream>>>(cdp, vd1, vd2, A_log, mod1, mod2, Aneg);
    k1_vdim1_inproj<<<NROWS / 32, 256, 0, stream>>>(x, mod1, ln1_w, ln1_b, in_proj, xsr, zsb);
    k2_conv_dbc_dt<<<NROWS / 64, 256, 0, stream>>>(xsr, conv_w, conv_b, x_proj, dt_w, dt_b,
                                                   xsc, dtb, Bmb, Cmb);
    s1_agg<<<NCT_, 384, 0, stream>>>(dtb, xsc, Bmb, Aneg, (float2*)aggf);
    s2_scan<<<B_ * NPAIR, 256, 0, stream>>>((const float2*)aggf, initb);
    s3_replay<<<NCT_, 384, 0, stream>>>(dtb, xsc, Bmb, Cmb, Aneg, initb, Dp, zsb, yb);
    k6_outproj<<<NROWS / 32, 256, 0, stream>>>(yb, opw, x, ss1, h1);
    k7_vdim2_mlp<<<NROWS / 32, 256, 0, stream>>>(h1, mod2, ln2_w, ln2_b, fc1_w, fc1_b,
                                                 fc2_w, fc2_b, ss2, (float*)d_out);
}